// Round 9
// baseline (60.593 us; speedup 1.0000x reference)
//
#include <hip/hip_runtime.h>
#include <hip/hip_bf16.h>

#define SEQ 1024

typedef __attribute__((ext_vector_type(8))) short s16x8;
typedef __attribute__((ext_vector_type(4))) float f32x4;
typedef __attribute__((ext_vector_type(2))) unsigned int u32x2;
typedef __attribute__((ext_vector_type(4))) unsigned int u32x4;
typedef __attribute__((ext_vector_type(2))) float f32x2;

// bf16 element offsets in workspace
//  P01[v0][v1][512] = b1 + G0[v0] + G1[v1]   (v=38 is the zero/pad row)
//  G2 [v][512]
//  P34[v3][v4][512] = G3[v3] + G4[v4]
#define P01P 0
#define G2P  (1521 * 512)
#define P34P (G2P + 39 * 512)
#define W2P  (P34P + 1521 * 512)
#define W3P  (W2P + 256 * 512)
#define W4P  (W3P + 64 * 512)
#define BF_END (W4P + 12 * 512)
// fp32 G scratch (5*39*512 floats) lives after the bf16 region (byte ofs BF_END*2, 4B-aligned)

// pack frag-groups for W2/W3/W4 (16x16 MFMA layout)
#define F2 (16 * 16)
#define F3 (8 * 8)
#define F4 (3 * 4)
#define FTOT (F2 + F3 + F4)

__device__ __forceinline__ unsigned int f2bf(float f) {
    unsigned int u = __float_as_uint(f);
    return (u + 0x7fffu + ((u >> 16) & 1u)) >> 16;   // RNE
}

__device__ __forceinline__ unsigned short bfbits(float f) {
    __hip_bfloat16 h = __float2bfloat16(f);
    unsigned short u;
    __builtin_memcpy(&u, &h, 2);
    return u;
}

__device__ __forceinline__ unsigned pk2(float a, float b) {
    return (unsigned)bfbits(a) | ((unsigned)bfbits(b) << 16);
}

__device__ __forceinline__ float bf2f(short x) {
    return __uint_as_float(((unsigned)(unsigned short)x) << 16);
}

// prep1: blocks [0,195) compute fp32 GF[j][v][o] = dot(W1[o][j*128..], emb[v]); rest pack W2/3/4
__global__ void prep1(const float* __restrict__ w1, const float* __restrict__ w2,
                      const float* __restrict__ w3, const float* __restrict__ w4,
                      const float* __restrict__ emb, unsigned short* __restrict__ dst) {
    if (blockIdx.x < 195) {
        float* gf = reinterpret_cast<float*>(dst + BF_END);
        const int j = blockIdx.x / 39;
        const int v = blockIdx.x % 39;
        const int o = threadIdx.x;               // 0..511
        if (v >= 38) { gf[(j * 39 + v) * 512 + o] = 0.f; return; }
        __shared__ float ev[128];
        if (threadIdx.x < 128) ev[threadIdx.x] = emb[v * 128 + threadIdx.x];
        __syncthreads();
        const float* wr = w1 + o * 640 + j * 128;
        float s = 0.f;
        #pragma unroll
        for (int e = 0; e < 128; e += 4) {
            const float4 a = *reinterpret_cast<const float4*>(wr + e);
            s += a.x * ev[e] + a.y * ev[e + 1] + a.z * ev[e + 2] + a.w * ev[e + 3];
        }
        gf[(j * 39 + v) * 512 + o] = s;
    } else {
        const int g = (blockIdx.x - 195) * 512 + threadIdx.x;
        if (g >= FTOT * 64) return;
        const int lane = g & 63;
        const int t    = g >> 6;
        const float* w; int K, N, KC, base, tl;
        if (t < F2)           { w = w2; K = 512; N = 256; KC = 16; base = W2P; tl = t; }
        else if (t < F2 + F3) { w = w3; K = 256; N = 128; KC = 8;  base = W3P; tl = t - F2; }
        else                  { w = w4; K = 128; N = 38;  KC = 4;  base = W4P; tl = t - F2 - F3; }
        const int ct  = tl / KC;
        const int kc  = tl - ct * KC;
        const int col = ct * 16 + (lane & 15);
        const int k0  = kc * 32 + (lane >> 4) * 8;
        unsigned short o8[8];
        #pragma unroll
        for (int e = 0; e < 8; ++e)
            o8[e] = (col < N) ? (unsigned short)f2bf(w[col * K + k0 + e]) : (unsigned short)0;
        *reinterpret_cast<s16x8*>(dst + base + (size_t)(tl * 64 + lane) * 8) =
            *reinterpret_cast<s16x8*>(o8);
    }
}

// prep2: build bf16 pair tables from fp32 GF
__global__ void prep2(const float* __restrict__ b1, unsigned short* __restrict__ dst) {
    const float* gf = reinterpret_cast<const float*>(dst + BF_END);
    const int o   = threadIdx.x;
    const int bid = blockIdx.x;
    if (bid < 1521) {
        const int v0 = bid / 39, v1 = bid % 39;
        const float s = b1[o] + gf[(0 * 39 + v0) * 512 + o] + gf[(1 * 39 + v1) * 512 + o];
        dst[P01P + bid * 512 + o] = bfbits(s);
    } else if (bid < 1560) {
        const int v = bid - 1521;
        dst[G2P + v * 512 + o] = bfbits(gf[(2 * 39 + v) * 512 + o]);
    } else {
        const int p = bid - 1560;
        const int v3 = p / 39, v4 = p % 39;
        dst[P34P + p * 512 + o] = bfbits(gf[(3 * 39 + v3) * 512 + o] + gf[(4 * 39 + v4) * 512 + o]);
    }
}

// LDS (48 KB, 512-thread block, 32 rows, 3 blocks/CU):
//   h1 @ 0     : 32 rows x 512 cols bf16, stride 1024  (32768 B)  -> later h3 (32 x 256B)
//   h2 @ 32768 : 32 rows x 256 cols bf16, stride 512   (16384 B)
//   tokLDS aliases h2 during phase 1 (h2 written only at GEMM2 epilogue)
#define H1S 0
#define H2S 32768
#define H3S 0

#define SWZ(b, row) ((b) ^ (((row) & 15) << 4))

__device__ __forceinline__ u32x2 pack_relu(f32x4 a, float4 b) {
    u32x2 r;
    r[0] = pk2(fmaxf(a[0] + b.x, 0.f), fmaxf(a[1] + b.y, 0.f));
    r[1] = pk2(fmaxf(a[2] + b.z, 0.f), fmaxf(a[3] + b.w, 0.f));
    return r;
}

__launch_bounds__(512, 6)
__global__ void fused_mlp(const int* __restrict__ tok,
                          const unsigned short* __restrict__ wbf,
                          const float* __restrict__ b2,
                          const float* __restrict__ b3,
                          const float* __restrict__ b4,
                          float* __restrict__ out) {
    __shared__ char smem[49152];
    const int tid  = threadIdx.x;
    const int lane = tid & 63;
    const int wave = tid >> 6;                 // 0..7
    const int l15  = lane & 15;
    const int l4   = lane >> 4;                // 0..3
    const int r0   = blockIdx.x * 32;
    const int s0   = r0 & (SEQ - 1);
    const int bat  = r0 >> 10;

    int* tokL = reinterpret_cast<int*>(smem + H2S);

    // ---------- stage context tokens (OOB -> 38, the zero table row)
    if (tid < 36) {
        const int sp = s0 - 2 + tid;
        tokL[tid] = (sp >= 0 && sp < SEQ) ? tok[bat * SEQ + sp] : 38;
    }
    __syncthreads();

    // ---------- phase 1: h1[row] = relu(P01[t0,t1] + G2[t2] + P34[t3,t4]) -> LDS bf16
    {
        const int row = tid >> 4;              // 0..31
        const int c16 = tid & 15;
        const int t0 = tokL[row],     t1 = tokL[row + 1], t2 = tokL[row + 2];
        const int t3 = tokL[row + 3], t4 = tokL[row + 4];
        const unsigned short* pa = wbf + P01P + (t0 * 39 + t1) * 512;
        const unsigned short* pb = wbf + G2P  + t2 * 512;
        const unsigned short* pc = wbf + P34P + (t3 * 39 + t4) * 512;
        #pragma unroll
        for (int it = 0; it < 4; ++it) {
            const int c8 = it * 16 + c16;      // 8-col chunk 0..63
            const s16x8 va = *reinterpret_cast<const s16x8*>(pa + c8 * 8);
            const s16x8 vb = *reinterpret_cast<const s16x8*>(pb + c8 * 8);
            const s16x8 vc = *reinterpret_cast<const s16x8*>(pc + c8 * 8);
            u32x4 wv;
            #pragma unroll
            for (int h = 0; h < 4; ++h) {
                const float e0 = bf2f(va[2 * h])     + bf2f(vb[2 * h])     + bf2f(vc[2 * h]);
                const float e1 = bf2f(va[2 * h + 1]) + bf2f(vb[2 * h + 1]) + bf2f(vc[2 * h + 1]);
                wv[h] = pk2(fmaxf(e0, 0.f), fmaxf(e1, 0.f));
            }
            *reinterpret_cast<u32x4*>(smem + H1S + SWZ(row * 1024 + c8 * 16, row)) = wv;
        }
    }
    __syncthreads();

    // ---------- GEMM2 (swapped): [32,512] -> [32,256]; wave owns ctiles {2w,2w+1} x 2 row-tiles
    {
        f32x4 acc[2][2];
        #pragma unroll
        for (int rt = 0; rt < 2; ++rt)
            #pragma unroll
            for (int ct = 0; ct < 2; ++ct) acc[rt][ct] = (f32x4){0.f, 0.f, 0.f, 0.f};
        for (int ks = 0; ks < 16; ++ks) {
            s16x8 xv[2];
            #pragma unroll
            for (int rt = 0; rt < 2; ++rt) {
                const int row = rt * 16 + l15;
                xv[rt] = *reinterpret_cast<const s16x8*>(
                    smem + H1S + SWZ(row * 1024 + ks * 64 + l4 * 16, row));
            }
            #pragma unroll
            for (int ct = 0; ct < 2; ++ct) {
                const s16x8 w = *reinterpret_cast<const s16x8*>(
                    wbf + W2P + (((wave * 2 + ct) * 16 + ks) * 64 + lane) * 8);
                #pragma unroll
                for (int rt = 0; rt < 2; ++rt)
                    acc[rt][ct] = __builtin_amdgcn_mfma_f32_16x16x32_bf16(w, xv[rt], acc[rt][ct], 0, 0, 0);
            }
        }
        #pragma unroll
        for (int ct = 0; ct < 2; ++ct) {
            const int col0 = (wave * 2 + ct) * 16 + l4 * 4;
            const float4 bb = *reinterpret_cast<const float4*>(b2 + col0);
            #pragma unroll
            for (int rt = 0; rt < 2; ++rt) {
                const int row = rt * 16 + l15;
                *reinterpret_cast<u32x2*>(smem + H2S + SWZ(row * 512 + col0 * 2, row)) =
                    pack_relu(acc[rt][ct], bb);
            }
        }
    }
    __syncthreads();

    // ---------- GEMM3 (swapped): [32,256] -> [32,128]; wave owns ctile=wave x 2 row-tiles
    {
        f32x4 acc[2];
        #pragma unroll
        for (int rt = 0; rt < 2; ++rt) acc[rt] = (f32x4){0.f, 0.f, 0.f, 0.f};
        for (int ks = 0; ks < 8; ++ks) {
            const s16x8 w = *reinterpret_cast<const s16x8*>(
                wbf + W3P + ((wave * 8 + ks) * 64 + lane) * 8);
            #pragma unroll
            for (int rt = 0; rt < 2; ++rt) {
                const int row = rt * 16 + l15;
                const s16x8 xv = *reinterpret_cast<const s16x8*>(
                    smem + H2S + SWZ(row * 512 + ks * 64 + l4 * 16, row));
                acc[rt] = __builtin_amdgcn_mfma_f32_16x16x32_bf16(w, xv, acc[rt], 0, 0, 0);
            }
        }
        const int col0 = wave * 16 + l4 * 4;
        const float4 bb = *reinterpret_cast<const float4*>(b3 + col0);
        #pragma unroll
        for (int rt = 0; rt < 2; ++rt) {
            const int row = rt * 16 + l15;
            *reinterpret_cast<u32x2*>(smem + H3S + SWZ(row * 256 + col0 * 2, row)) =
                pack_relu(acc[rt], bb);
        }
    }
    __syncthreads();

    // ---------- GEMM4 (swapped): [32,128] -> out[32,38]; waves 0..5: rt=w&1, mt=w>>1
    if (wave < 6) {
        const int rt = wave & 1;
        const int mt = wave >> 1;              // W4 col tile 0..2
        f32x4 acc = (f32x4){0.f, 0.f, 0.f, 0.f};
        #pragma unroll
        for (int ks = 0; ks < 4; ++ks) {
            const int row = rt * 16 + l15;
            const s16x8 xv = *reinterpret_cast<const s16x8*>(
                smem + H3S + SWZ(row * 256 + ks * 64 + l4 * 16, row));
            const s16x8 w = *reinterpret_cast<const s16x8*>(
                wbf + W4P + ((mt * 4 + ks) * 64 + lane) * 8);
            acc = __builtin_amdgcn_mfma_f32_16x16x32_bf16(w, xv, acc, 0, 0, 0);
        }
        const int rg   = r0 + rt * 16 + l15;
        const int col0 = mt * 16 + l4 * 4;
        #pragma unroll
        for (int h = 0; h < 2; ++h) {
            const int c = col0 + 2 * h;
            if (c < 38) {
                f32x2 v;
                v[0] = acc[2 * h]     + b4[c];
                v[1] = acc[2 * h + 1] + b4[c + 1];
                *reinterpret_cast<f32x2*>(out + rg * 38 + c) = v;
            }
        }
    }
}

extern "C" void kernel_launch(void* const* d_in, const int* in_sizes, int n_in,
                              void* d_out, int out_size, void* d_ws, size_t ws_size,
                              hipStream_t stream) {
    const int*   tok = (const int*)d_in[0];
    const float* emb = (const float*)d_in[1];
    const float* W1  = (const float*)d_in[2];
    const float* b1  = (const float*)d_in[3];
    const float* W2  = (const float*)d_in[4];
    const float* b2  = (const float*)d_in[5];
    const float* W3  = (const float*)d_in[6];
    const float* b3  = (const float*)d_in[7];
    const float* W4  = (const float*)d_in[8];
    const float* b4  = (const float*)d_in[9];
    float* out = (float*)d_out;
    unsigned short* wbf = (unsigned short*)d_ws;

    const int pack_blocks = (FTOT * 64 + 511) / 512;     // 42
    prep1<<<195 + pack_blocks, 512, 0, stream>>>(W1, W2, W3, W4, emb, wbf);
    prep2<<<1521 + 39 + 1521, 512, 0, stream>>>(b1, wbf);
    fused_mlp<<<2048, 512, 0, stream>>>(tok, wbf, b2, b3, b4, out);
}